// Round 8
// baseline (217.948 us; speedup 1.0000x reference)
//
#include <hip/hip_runtime.h>
#include <hip/hip_bf16.h>
#include <cstring>

// GraphSAGE 2-layer, CSR-gather formulation (no float atomics).
//   h1 = relu(x@Ws1 + mean_agg(x)@Wn1 + b1)
//   out = h1@Ws2 + mean_agg(h1)@Wn2 + b2
// mean_agg(h)@W == mean_agg(h@W): project first, then aggregate projected rows.
// R21: DISPATCH-COUNT attack (6 -> 4). Budget model (R16-R20 consistent):
//   dur ~= 45us poison-fill + ~8us/dispatch + ~50us kernels.
//  (a) memset dispatch deleted: per-(bucket,block) fixed epart segments
//      (CAPB=64, 256B-aligned -> no false sharing) + non-atomic blkcnt table.
//      NOTHING needs pre-zeroed workspace. Partition simpler (1 atomic pass).
//  (b) gemm2 dispatch deleted: final gather fuses the dual matvec
//      out = h1@Ws2 + (agg_h1/d)@Wn2 + b2 per wave-per-node (lane = k-slice x
//      2 cols; agg via uniform-shfl broadcast row loads, depth-2 preserved).
//      Kills t2 round trip + its bf16 rounding + outp RMW. W is 8KB, L1-hot.
// t1 fp8 e4m3 (3.2 MB, L2-resident gather table); selfo bf16; fp32 acc.
// Closed experiment families:
//  R9:  LDS float-atomic aggregation -> 356 us disaster (serialized RMW).
//  R11: gather byte-shrink (fp8) -> small win; gathers are L2-hit LATENCY bound.
//  R13: wide-load instr-rate reduction -> neutral (confirms latency-bound).
//  R14: per-node in-wave gemm2 fusion -> regression (destroys W-tile reuse;
//       N/A here: W=8KB L1-resident, no tile staging to lose).
//  R15: fixed-depth predicated gathers -> small win (-4.4us).
//  R16: direct-slot CSR scatter -> +24us (random-line 4B writes, 56.7MB WRITE).
//  R17: bucket partition + single-pass fixed-cap CSR build -> 152.5us (BEST).
//  R18: cooperative mega-kernel -> 483.7us (grid.sync flushes 8 XCD L2s).
//  R19: gather+gemm2 block fusion -> 96us alone (node serialization killed TLP).
//  R20: cross-block global-atomic buildcsr + ushort csr -> +7.8us (cross-XCD
//       line ping-pong on shared node rows). buildcsr stays block-per-bucket.

#define FEATS 64
#define CLS   16
#define EPT   16      // edges/thread in partition role (4096 edges/block)
#define CAPB  64      // per-(bucket,block) epart segment capacity (mean 21, +9sigma)
#define CAPN  64      // per-node CSR row capacity (Poisson(16): P[d>64]~1e-18)

typedef unsigned short bf16_t;
typedef float floatx2 __attribute__((ext_vector_type(2)));

__device__ __forceinline__ float bfbits2f(unsigned lo16) {
    unsigned v = lo16 << 16;
    float f;
    __builtin_memcpy(&f, &v, 4);
    return f;
}
__device__ __forceinline__ float bf_lo(unsigned u) {   // low bf16 -> f32 (1 op)
    unsigned v = u << 16;
    float f;
    __builtin_memcpy(&f, &v, 4);
    return f;
}
__device__ __forceinline__ float bf_hi(unsigned u) {   // high bf16 -> f32 (1 op)
    unsigned v = u & 0xffff0000u;
    float f;
    __builtin_memcpy(&f, &v, 4);
    return f;
}
__device__ __forceinline__ bf16_t f2bf(float f) {
    unsigned u;
    __builtin_memcpy(&u, &f, 4);
    u = (u + 0x7FFFu + ((u >> 16) & 1u)) >> 16;   // round-to-nearest-even
    return (bf16_t)u;
}
__device__ __forceinline__ unsigned pack2(float a, float b) {
    return (unsigned)f2bf(a) | ((unsigned)f2bf(b) << 16);
}
// pack 4 f32 -> 4 fp8 e4m3 in one dword (HW cvt, RNE)
__device__ __forceinline__ unsigned pack4_fp8(float a, float b, float c, float d) {
    int q = __builtin_amdgcn_cvt_pk_fp8_f32(a, b, 0, false);
    q = __builtin_amdgcn_cvt_pk_fp8_f32(c, d, q, true);
    return (unsigned)q;
}

// ---------------- fused: partition (blocks [0,nbp)) + GEMM1 (blocks [nbp, nbp+nbg)) ----------------
// Partition v2: per-(bucket,block) fixed segments; LDS hist slot alloc only;
// blkcnt[blk*256 + bucket] written non-atomically. No pre-zeroed globals.
__global__ __launch_bounds__(256) void fused_pg_kernel(
    const int* __restrict__ src, const int* __restrict__ dst,
    int* __restrict__ blkcnt, int* __restrict__ epart, int E,
    const float* __restrict__ x, const float* __restrict__ Ws,
    const float* __restrict__ Wn, bf16_t* __restrict__ selfo,
    unsigned char* __restrict__ t1, int N, int nbp)
{
    __shared__ float smem[16512];   // 66 KB: gemm1 Wc[8192]+xs[8320]; partition hist
    int t = threadIdx.x;

    if ((int)blockIdx.x < nbp) {
        // ---- partition role: one LDS-atomic pass into own 256B-aligned segments ----
        int* hist = (int*)smem;
        int e0 = blockIdx.x * (256 * EPT);
        hist[t] = 0;
        __syncthreads();
#pragma unroll
        for (int j = 0; j < EPT; ++j) {
            int e = e0 + j * 256 + t;
            if (e < E) {
                int d = dst[e];
                int pk = (src[e] << 8) | (d & 255);
                int bk = d >> 8;
                int r = atomicAdd(&hist[bk], 1);
                if (r < CAPB)
                    epart[((size_t)bk * nbp + blockIdx.x) * CAPB + r] = pk;
            }
        }
        __syncthreads();
        blkcnt[(size_t)blockIdx.x * 256 + t] = hist[t];   // coalesced 1KB row
        return;
    }

    // ---- gemm1 role ----
    float* Wc = smem;           // 64*128
    float* xs = smem + 8192;    // 128*65
    int node0 = ((int)blockIdx.x - nbp) * 128;

    for (int idx = t; idx < 64 * 128; idx += 256) {
        int k = idx >> 7, c = idx & 127;
        Wc[idx] = (c < 64) ? Ws[k * 64 + c] : Wn[k * 64 + (c - 64)];
    }
    for (int idx = t; idx < 128 * 16; idx += 256) {
        int row = idx >> 4, c4 = idx & 15;
        int node = node0 + row;
        float4 v = (node < N) ? ((const float4*)(x + (size_t)node * 64))[c4]
                              : make_float4(0.f, 0.f, 0.f, 0.f);
        float* p = &xs[row * 65 + c4 * 4];
        p[0] = v.x; p[1] = v.y; p[2] = v.z; p[3] = v.w;
    }
    __syncthreads();

    int m = t & 31;
    int g = t >> 5;            // 8 col-groups of 16
    float acc[4][16];
#pragma unroll
    for (int j = 0; j < 4; ++j)
#pragma unroll
        for (int c = 0; c < 16; ++c) acc[j][c] = 0.f;

    for (int k = 0; k < 64; ++k) {
        float w[16];
        const float* wp = &Wc[k * 128 + g * 16];
#pragma unroll
        for (int c = 0; c < 16; ++c) w[c] = wp[c];
        float a0 = xs[m * 65 + k];
        float a1 = xs[(m + 32) * 65 + k];
        float a2 = xs[(m + 64) * 65 + k];
        float a3 = xs[(m + 96) * 65 + k];
#pragma unroll
        for (int c = 0; c < 16; ++c) {
            acc[0][c] += a0 * w[c];
            acc[1][c] += a1 * w[c];
            acc[2][c] += a2 * w[c];
            acc[3][c] += a3 * w[c];
        }
    }
#pragma unroll
    for (int j = 0; j < 4; ++j) {
        int node = node0 + m + 32 * j;
        if (node < N) {
            if (g < 4) {
                bf16_t* dstp = selfo + (size_t)node * 64 + g * 16;
                uint4 p0, p1;
                p0.x = pack2(acc[j][0],  acc[j][1]);  p0.y = pack2(acc[j][2],  acc[j][3]);
                p0.z = pack2(acc[j][4],  acc[j][5]);  p0.w = pack2(acc[j][6],  acc[j][7]);
                p1.x = pack2(acc[j][8],  acc[j][9]);  p1.y = pack2(acc[j][10], acc[j][11]);
                p1.z = pack2(acc[j][12], acc[j][13]); p1.w = pack2(acc[j][14], acc[j][15]);
                *(uint4*)(dstp) = p0;
                *(uint4*)(dstp + 8) = p1;
            } else {
                unsigned char* dstp = t1 + (size_t)node * 64 + (g - 4) * 16;
                uint4 q;
                q.x = pack4_fp8(acc[j][0],  acc[j][1],  acc[j][2],  acc[j][3]);
                q.y = pack4_fp8(acc[j][4],  acc[j][5],  acc[j][6],  acc[j][7]);
                q.z = pack4_fp8(acc[j][8],  acc[j][9],  acc[j][10], acc[j][11]);
                q.w = pack4_fp8(acc[j][12], acc[j][13], acc[j][14], acc[j][15]);
                *(uint4*)(dstp) = q;
            }
        }
    }
}

// ---------------- bucket -> fixed-capacity CSR rows (block-per-bucket, R17 shape) ----------------
// Validity from blkcnt segments (no bucket total needed). LDS node counters.
__global__ __launch_bounds__(256) void buildcsr_kernel(const int* __restrict__ epart,
                                                       const int* __restrict__ blkcnt,
                                                       int* __restrict__ cnt,
                                                       int* __restrict__ csr,
                                                       int N, int nbp) {
    __shared__ int cseg[256];     // per-partition-block count for this bucket
    __shared__ int nodecnt[256];
    int t = threadIdx.x;
    int b = blockIdx.x;
    cseg[t] = (t < nbp) ? blkcnt[(size_t)t * 256 + b] : 0;
    nodecnt[t] = 0;
    __syncthreads();
    int total = nbp * CAPB;
    for (int idx = t; idx < total; idx += 256) {
        int i = idx >> 6;          // CAPB = 64
        int r = idx & 63;
        if (r < cseg[i]) {
            int pk = epart[((size_t)b * nbp + i) * CAPB + r];
            int ln = pk & 255;
            int s = atomicAdd(&nodecnt[ln], 1);
            if (s < CAPN) csr[(size_t)(b * 256 + ln) * CAPN + s] = pk >> 8;
        }
    }
    __syncthreads();
    int node = b * 256 + t;
    if (node < N) cnt[node] = nodecnt[t];
}

// ---------------- gather64: h1 = relu(selfo + (sum t1[src])/deg + b1) ----------------
// one wave per node; lane = (eslot, cg): 4 edge slots x 16 col-groups (dword = 4 fp8).
// Row base computable (wid*64): csr row load + cnt load both issue at cycle 0;
// edge select via __shfl with d-clamped index; strict depth 2. (R17-proven.)
__global__ __launch_bounds__(256) void gather64_kernel(
    const int* __restrict__ csr, const int* __restrict__ cnt,
    const unsigned char* __restrict__ t1, const bf16_t* __restrict__ selfo,
    bf16_t* __restrict__ h1, const float* __restrict__ b1, int N)
{
    int wid = (blockIdx.x * 256 + threadIdx.x) >> 6;
    int lane = threadIdx.x & 63;
    int eslot = lane >> 4;       // 0..3
    int cg = lane & 15;          // cols [cg*4, cg*4+4)
    if (wid >= N) return;
    int eraw = csr[(size_t)wid * CAPN + lane];   // whole row, coalesced, no deps
    int d = cnt[wid];                            // parallel with eraw
    size_t o = (size_t)wid * 64 + cg * 4;
    uint2 su;
    float4 bb;
    if (eslot == 0) {
        su = *(const uint2*)(selfo + o);
        bb = *(const float4*)(b1 + cg * 4);
    }
    d = min(d, CAPN);
    float ax = 0.f, ay = 0.f, az = 0.f, aw = 0.f;
    if (d > 0) {
        int dm1 = d - 1;
#define G64_ACC(r, m)                                                      \
        {                                                                  \
            floatx2 p_ = __builtin_amdgcn_cvt_pk_f32_fp8((int)(r), false); \
            floatx2 q_ = __builtin_amdgcn_cvt_pk_f32_fp8((int)(r), true);  \
            ax += (m) * p_.x; ay += (m) * p_.y;                            \
            az += (m) * q_.x; aw += (m) * q_.y;                            \
        }
#define G64_BATCH(KN)                                                      \
        {                                                                  \
            int ss[KN];                                                    \
            float mk[KN];                                                  \
            unsigned rr[KN];                                               \
            _Pragma("unroll")                                              \
            for (int k = 0; k < KN; ++k) {                                 \
                int i = eslot + 4 * k;                                     \
                int idx = i > dm1 ? dm1 : i;                               \
                mk[k] = (i <= dm1) ? 1.f : 0.f;                            \
                ss[k] = __shfl(eraw, idx);                                 \
            }                                                              \
            _Pragma("unroll")                                              \
            for (int k = 0; k < KN; ++k)                                   \
                rr[k] = *(const unsigned*)(t1 + (size_t)ss[k] * 64 + cg * 4); \
            _Pragma("unroll")                                              \
            for (int k = 0; k < KN; ++k) G64_ACC(rr[k], mk[k]);            \
        }
        if (d <= 16) {
            G64_BATCH(4)
        } else if (d <= 32) {
            G64_BATCH(8)
        } else {
            G64_BATCH(16)   // rare (P[d>32] ~ 1e-4): full row, still depth 2
        }
#undef G64_BATCH
#undef G64_ACC
        ax += __shfl_xor(ax, 16); ay += __shfl_xor(ay, 16);
        az += __shfl_xor(az, 16); aw += __shfl_xor(aw, 16);
        ax += __shfl_xor(ax, 32); ay += __shfl_xor(ay, 32);
        az += __shfl_xor(az, 32); aw += __shfl_xor(aw, 32);
    }
    if (eslot == 0) {
        float inv = 1.f / fmaxf((float)d, 1.f);
        float rx = fmaxf(bfbits2f(su.x & 0xffff) + ax * inv + bb.x, 0.f);
        float ry = fmaxf(bfbits2f(su.x >> 16)    + ay * inv + bb.y, 0.f);
        float rz = fmaxf(bfbits2f(su.y & 0xffff) + az * inv + bb.z, 0.f);
        float rw = fmaxf(bfbits2f(su.y >> 16)    + aw * inv + bb.w, 0.f);
        uint2 pk;
        pk.x = pack2(rx, ry);
        pk.y = pack2(rz, rw);
        *(uint2*)(h1 + o) = pk;
    }
}

// ---------------- gather16f: out = h1@Ws2 + (agg_h1/d)@Wn2 + b2 (gemm2 fused) ----------------
// one wave per node; lane (ks,c2): ks = k-slice [8ks,8ks+8), c2 = 2 output cols.
// Neighbor rows loaded with uniform shfl index (broadcast); every lane holds the
// full agg for ITS k-slice -> per-lane dual matvec, xor-reduce over ks. Depth 2.
__global__ __launch_bounds__(256) void gather16f_kernel(
    const int* __restrict__ csr, const int* __restrict__ cnt,
    const bf16_t* __restrict__ h1,
    const float* __restrict__ Ws2, const float* __restrict__ Wn2,
    const float* __restrict__ b2, float* __restrict__ outp, int N)
{
    int wid = (blockIdx.x * 256 + threadIdx.x) >> 6;
    int lane = threadIdx.x & 63;
    int ks = lane >> 3;          // 0..7: k in [ks*8, ks*8+8)
    int c2 = lane & 7;           // cols {2*c2, 2*c2+1}
    if (wid >= N) return;
    int eraw = csr[(size_t)wid * CAPN + lane];   // whole row, coalesced
    int d = cnt[wid];                            // parallel with eraw
    // own h1 slice + W slices + bias: all issue early, hide under gather
    uint4 own = *(const uint4*)(h1 + (size_t)wid * 64 + ks * 8);
    float ws[8][2], wn[8][2];
#pragma unroll
    for (int k = 0; k < 8; ++k) {
        float2 a = *(const float2*)(Ws2 + (ks * 8 + k) * 16 + c2 * 2);
        float2 q = *(const float2*)(Wn2 + (ks * 8 + k) * 16 + c2 * 2);
        ws[k][0] = a.x; ws[k][1] = a.y;
        wn[k][0] = q.x; wn[k][1] = q.y;
    }
    float2 bbv = *(const float2*)(b2 + c2 * 2);
    d = min(d, CAPN);
    float agg[8];
#pragma unroll
    for (int k = 0; k < 8; ++k) agg[k] = 0.f;
    if (d > 0) {
        int dm1 = d - 1;
#define G16F_BATCH(KB)                                                     \
        {                                                                  \
            uint4 vv[8]; float mk[8];                                      \
            _Pragma("unroll")                                              \
            for (int q = 0; q < 8; ++q) {                                  \
                int i = (KB) * 8 + q;                                      \
                int ix = i > dm1 ? dm1 : i;                                \
                mk[q] = (i <= dm1) ? 1.f : 0.f;                            \
                int nb = __shfl(eraw, ix);                                 \
                vv[q] = *(const uint4*)(h1 + (size_t)nb * 64 + ks * 8);    \
            }                                                              \
            _Pragma("unroll")                                              \
            for (int q = 0; q < 8; ++q) {                                  \
                float m = mk[q]; uint4 v = vv[q];                          \
                agg[0] += m * bf_lo(v.x); agg[1] += m * bf_hi(v.x);        \
                agg[2] += m * bf_lo(v.y); agg[3] += m * bf_hi(v.y);        \
                agg[4] += m * bf_lo(v.z); agg[5] += m * bf_hi(v.z);        \
                agg[6] += m * bf_lo(v.w); agg[7] += m * bf_hi(v.w);        \
            }                                                              \
        }
        if (d <= 8) {
            G16F_BATCH(0)
        } else if (d <= 16) {
            G16F_BATCH(0) G16F_BATCH(1)
        } else if (d <= 32) {
            G16F_BATCH(0) G16F_BATCH(1) G16F_BATCH(2) G16F_BATCH(3)
        } else {
            for (int i = 0; i < d; ++i) {      // rare (P[d>32] ~ 1e-4)
                int nb = __shfl(eraw, i);
                uint4 v = *(const uint4*)(h1 + (size_t)nb * 64 + ks * 8);
                agg[0] += bf_lo(v.x); agg[1] += bf_hi(v.x);
                agg[2] += bf_lo(v.y); agg[3] += bf_hi(v.y);
                agg[4] += bf_lo(v.z); agg[5] += bf_hi(v.z);
                agg[6] += bf_lo(v.w); agg[7] += bf_hi(v.w);
            }
        }
#undef G16F_BATCH
    }
    // dual matvec for this lane's k-slice and 2 cols
    float inv = 1.f / fmaxf((float)d, 1.f);
    float p0 = 0.f, p1 = 0.f;
    {
        float hv, av;
        unsigned uu[4] = {own.x, own.y, own.z, own.w};
#pragma unroll
        for (int k = 0; k < 4; ++k) {
            hv = bf_lo(uu[k]); av = agg[2 * k] * inv;
            p0 += hv * ws[2 * k][0] + av * wn[2 * k][0];
            p1 += hv * ws[2 * k][1] + av * wn[2 * k][1];
            hv = bf_hi(uu[k]); av = agg[2 * k + 1] * inv;
            p0 += hv * ws[2 * k + 1][0] + av * wn[2 * k + 1][0];
            p1 += hv * ws[2 * k + 1][1] + av * wn[2 * k + 1][1];
        }
    }
    // reduce over ks (lane bits 3,4,5)
    p0 += __shfl_xor(p0, 8);  p1 += __shfl_xor(p1, 8);
    p0 += __shfl_xor(p0, 16); p1 += __shfl_xor(p1, 16);
    p0 += __shfl_xor(p0, 32); p1 += __shfl_xor(p1, 32);
    if (ks == 0) {
        float2 r;
        r.x = p0 + bbv.x;
        r.y = p1 + bbv.y;
        *(float2*)(outp + (size_t)wid * 16 + c2 * 2) = r;
    }
}

extern "C" void kernel_launch(void* const* d_in, const int* in_sizes, int n_in,
                              void* d_out, int out_size, void* d_ws, size_t ws_size,
                              hipStream_t stream) {
    const float* x   = (const float*)d_in[0];
    const int*   src = (const int*)d_in[1];
    const int*   dst = (const int*)d_in[2];
    const float* Ws1 = (const float*)d_in[3];
    const float* Wn1 = (const float*)d_in[4];
    const float* b1  = (const float*)d_in[5];
    const float* Ws2 = (const float*)d_in[6];
    const float* Wn2 = (const float*)d_in[7];
    const float* b2  = (const float*)d_in[8];
    float* outp = (float*)d_out;

    const int N = in_sizes[0] / FEATS;   // 50000
    const int E = in_sizes[1];           // 800000
    const int B = (N + 255) / 256;       // buckets (196) — must be <= 256
    const int NBP = (E + 256 * EPT - 1) / (256 * EPT);   // partition blocks (196)
    const int NBG = (N + 127) / 128;                     // gemm1 blocks (391)

    // workspace (nothing pre-zeroed): blkcnt[NBP*256] | epart[B*NBP*CAPB] |
    //   cnt[N] | csr[N*CAPN] | selfo bf16[N*64] | t1 fp8[N*64] | h1 bf16[N*64]
    char* p = (char*)d_ws;
    auto align16 = [](char* q) { return (char*)(((size_t)q + 15) & ~(size_t)15); };
    int* blkcnt        = (int*)p;                  p = (char*)(blkcnt + (size_t)NBP * 256);
    int* epart         = (int*)align16(p);         p = (char*)(epart + (size_t)B * NBP * CAPB);
    int* cnt           = (int*)align16(p);         p = (char*)(cnt + N);
    int* csr           = (int*)align16(p);         p = (char*)(csr + (size_t)N * CAPN);
    bf16_t* selfo      = (bf16_t*)align16(p);      p = (char*)(selfo + (size_t)N * 64);
    unsigned char* t1  = (unsigned char*)align16(p); p = (char*)(t1 + (size_t)N * 64);
    bf16_t* h1         = (bf16_t*)align16(p);

    fused_pg_kernel<<<NBP + NBG, 256, 0, stream>>>(
        src, dst, blkcnt, epart, E, x, Ws1, Wn1, selfo, t1, N, NBP);
    buildcsr_kernel<<<B, 256, 0, stream>>>(epart, blkcnt, cnt, csr, N, NBP);

    gather64_kernel<<<((size_t)N * 64 + 255) / 256, 256, 0, stream>>>(
        csr, cnt, t1, selfo, h1, b1, N);
    gather16f_kernel<<<((size_t)N * 64 + 255) / 256, 256, 0, stream>>>(
        csr, cnt, h1, Ws2, Wn2, b2, outp, N);
}

// Round 9
// 160.177 us; speedup vs baseline: 1.3607x; 1.3607x over previous
//
#include <hip/hip_runtime.h>
#include <hip/hip_bf16.h>
#include <cstring>

// GraphSAGE 2-layer, CSR-gather formulation (no float atomics).
//   h1 = relu(x@Ws1 + mean_agg(x)@Wn1 + b1)
//   out = h1@Ws2 + mean_agg(h1)@Wn2 + b2
// mean_agg(h)@W == mean_agg(h@W): project first, then aggregate projected rows.
// R22 = R21a + R17 tail: segment partition (no memset dispatch, no global
//   atomics) + block-per-bucket buildcsr + R17-proven gather64/gemm2/gather16.
//   5 dispatches. Aggregation stays in SMALLEST projected space (t1 fp8 3.2MB,
//   t2 bf16 1.6MB — both < 4MiB per-XCD L2).
// Closed experiment families:
//  R9:  LDS float-atomic aggregation -> 356 us disaster (serialized RMW).
//  R11: gather byte-shrink (fp8) -> small win; gathers are L2-hit LATENCY bound.
//  R13: wide-load instr-rate reduction -> neutral (confirms latency-bound).
//  R14: per-node in-wave gemm2 fusion -> regression (destroys W-tile reuse).
//  R15: fixed-depth predicated gathers -> small win (-4.4us).
//  R16: direct-slot CSR scatter -> +24us (random-line 4B writes, 56.7MB WRITE).
//  R17: bucket partition + single-pass fixed-cap CSR build -> 152.5us (prev BEST).
//  R18: cooperative mega-kernel -> 483.7us (grid.sync flushes 8 XCD L2s).
//  R19: gather+gemm2 block fusion -> 96us alone (node serialization killed TLP).
//  R20: cross-block global-atomic buildcsr -> +7.8us (cross-XCD line ping-pong).
//  R21: gemm2-into-gather fusion -> gather16f 87us alone, FETCH 57.6MB:
//       aggregating 64-dim h1 (102MB reads, 6.4MB table > 4MiB per-XCD L2)
//       instead of 16-dim t2 (25.6MB reads, 1.6MB table). AGGREGATE IN THE
//       PROJECTED SPACE; keep gather tables < 4MiB.

#define FEATS 64
#define CLS   16
#define EPT   16      // edges/thread in partition role (4096 edges/block)
#define CAPB  64      // per-(bucket,block) epart segment capacity (mean 21, +9sigma)
#define CAPN  64      // per-node CSR row capacity (Poisson(16): P[d>64]~1e-18)

typedef unsigned short bf16_t;
typedef float floatx2 __attribute__((ext_vector_type(2)));

__device__ __forceinline__ float bfbits2f(unsigned lo16) {
    unsigned v = lo16 << 16;
    float f;
    __builtin_memcpy(&f, &v, 4);
    return f;
}
__device__ __forceinline__ bf16_t f2bf(float f) {
    unsigned u;
    __builtin_memcpy(&u, &f, 4);
    u = (u + 0x7FFFu + ((u >> 16) & 1u)) >> 16;   // round-to-nearest-even
    return (bf16_t)u;
}
__device__ __forceinline__ unsigned pack2(float a, float b) {
    return (unsigned)f2bf(a) | ((unsigned)f2bf(b) << 16);
}
// pack 4 f32 -> 4 fp8 e4m3 in one dword (HW cvt, RNE)
__device__ __forceinline__ unsigned pack4_fp8(float a, float b, float c, float d) {
    int q = __builtin_amdgcn_cvt_pk_fp8_f32(a, b, 0, false);
    q = __builtin_amdgcn_cvt_pk_fp8_f32(c, d, q, true);
    return (unsigned)q;
}

// ---------------- fused: partition (blocks [0,nbp)) + GEMM1 (blocks [nbp, nbp+nbg)) ----------------
// Partition: per-(bucket,block) fixed segments; LDS hist slot alloc only;
// blkcnt[blk*256 + bucket] written non-atomically. No pre-zeroed globals.
__global__ __launch_bounds__(256) void fused_pg_kernel(
    const int* __restrict__ src, const int* __restrict__ dst,
    int* __restrict__ blkcnt, int* __restrict__ epart, int E,
    const float* __restrict__ x, const float* __restrict__ Ws,
    const float* __restrict__ Wn, bf16_t* __restrict__ selfo,
    unsigned char* __restrict__ t1, int N, int nbp)
{
    __shared__ float smem[16512];   // 66 KB: gemm1 Wc[8192]+xs[8320]; partition hist
    int t = threadIdx.x;

    if ((int)blockIdx.x < nbp) {
        // ---- partition role: one LDS-atomic pass into own 256B-aligned segments ----
        int* hist = (int*)smem;
        int e0 = blockIdx.x * (256 * EPT);
        hist[t] = 0;
        __syncthreads();
#pragma unroll
        for (int j = 0; j < EPT; ++j) {
            int e = e0 + j * 256 + t;
            if (e < E) {
                int d = dst[e];
                int pk = (src[e] << 8) | (d & 255);
                int bk = d >> 8;
                int r = atomicAdd(&hist[bk], 1);
                if (r < CAPB)
                    epart[((size_t)bk * nbp + blockIdx.x) * CAPB + r] = pk;
            }
        }
        __syncthreads();
        blkcnt[(size_t)blockIdx.x * 256 + t] = hist[t];   // coalesced 1KB row
        return;
    }

    // ---- gemm1 role ----
    float* Wc = smem;           // 64*128
    float* xs = smem + 8192;    // 128*65
    int node0 = ((int)blockIdx.x - nbp) * 128;

    for (int idx = t; idx < 64 * 128; idx += 256) {
        int k = idx >> 7, c = idx & 127;
        Wc[idx] = (c < 64) ? Ws[k * 64 + c] : Wn[k * 64 + (c - 64)];
    }
    for (int idx = t; idx < 128 * 16; idx += 256) {
        int row = idx >> 4, c4 = idx & 15;
        int node = node0 + row;
        float4 v = (node < N) ? ((const float4*)(x + (size_t)node * 64))[c4]
                              : make_float4(0.f, 0.f, 0.f, 0.f);
        float* p = &xs[row * 65 + c4 * 4];
        p[0] = v.x; p[1] = v.y; p[2] = v.z; p[3] = v.w;
    }
    __syncthreads();

    int m = t & 31;
    int g = t >> 5;            // 8 col-groups of 16
    float acc[4][16];
#pragma unroll
    for (int j = 0; j < 4; ++j)
#pragma unroll
        for (int c = 0; c < 16; ++c) acc[j][c] = 0.f;

    for (int k = 0; k < 64; ++k) {
        float w[16];
        const float* wp = &Wc[k * 128 + g * 16];
#pragma unroll
        for (int c = 0; c < 16; ++c) w[c] = wp[c];
        float a0 = xs[m * 65 + k];
        float a1 = xs[(m + 32) * 65 + k];
        float a2 = xs[(m + 64) * 65 + k];
        float a3 = xs[(m + 96) * 65 + k];
#pragma unroll
        for (int c = 0; c < 16; ++c) {
            acc[0][c] += a0 * w[c];
            acc[1][c] += a1 * w[c];
            acc[2][c] += a2 * w[c];
            acc[3][c] += a3 * w[c];
        }
    }
#pragma unroll
    for (int j = 0; j < 4; ++j) {
        int node = node0 + m + 32 * j;
        if (node < N) {
            if (g < 4) {
                bf16_t* dstp = selfo + (size_t)node * 64 + g * 16;
                uint4 p0, p1;
                p0.x = pack2(acc[j][0],  acc[j][1]);  p0.y = pack2(acc[j][2],  acc[j][3]);
                p0.z = pack2(acc[j][4],  acc[j][5]);  p0.w = pack2(acc[j][6],  acc[j][7]);
                p1.x = pack2(acc[j][8],  acc[j][9]);  p1.y = pack2(acc[j][10], acc[j][11]);
                p1.z = pack2(acc[j][12], acc[j][13]); p1.w = pack2(acc[j][14], acc[j][15]);
                *(uint4*)(dstp) = p0;
                *(uint4*)(dstp + 8) = p1;
            } else {
                unsigned char* dstp = t1 + (size_t)node * 64 + (g - 4) * 16;
                uint4 q;
                q.x = pack4_fp8(acc[j][0],  acc[j][1],  acc[j][2],  acc[j][3]);
                q.y = pack4_fp8(acc[j][4],  acc[j][5],  acc[j][6],  acc[j][7]);
                q.z = pack4_fp8(acc[j][8],  acc[j][9],  acc[j][10], acc[j][11]);
                q.w = pack4_fp8(acc[j][12], acc[j][13], acc[j][14], acc[j][15]);
                *(uint4*)(dstp) = q;
            }
        }
    }
}

// ---------------- bucket -> fixed-capacity CSR rows (block-per-bucket, R17 shape) ----------------
// Validity from blkcnt segments (no bucket total needed). LDS node counters.
__global__ __launch_bounds__(256) void buildcsr_kernel(const int* __restrict__ epart,
                                                       const int* __restrict__ blkcnt,
                                                       int* __restrict__ cnt,
                                                       int* __restrict__ csr,
                                                       int N, int nbp) {
    __shared__ int cseg[256];     // per-partition-block count for this bucket
    __shared__ int nodecnt[256];
    int t = threadIdx.x;
    int b = blockIdx.x;
    cseg[t] = (t < nbp) ? blkcnt[(size_t)t * 256 + b] : 0;
    nodecnt[t] = 0;
    __syncthreads();
    int total = nbp * CAPB;
    for (int idx = t; idx < total; idx += 256) {
        int i = idx >> 6;          // CAPB = 64
        int r = idx & 63;
        if (r < cseg[i]) {
            int pk = epart[((size_t)b * nbp + i) * CAPB + r];
            int ln = pk & 255;
            int s = atomicAdd(&nodecnt[ln], 1);
            if (s < CAPN) csr[(size_t)(b * 256 + ln) * CAPN + s] = pk >> 8;
        }
    }
    __syncthreads();
    int node = b * 256 + t;
    if (node < N) cnt[node] = nodecnt[t];
}

// ---------------- gather64: h1 = relu(selfo + (sum t1[src])/deg + b1) ----------------
// one wave per node; lane = (eslot, cg): 4 edge slots x 16 col-groups (dword = 4 fp8).
// Row base computable (wid*64): csr row load + cnt load both issue at cycle 0;
// edge select via __shfl with d-clamped index; strict depth 2. (R17-proven.)
__global__ __launch_bounds__(256) void gather64_kernel(
    const int* __restrict__ csr, const int* __restrict__ cnt,
    const unsigned char* __restrict__ t1, const bf16_t* __restrict__ selfo,
    bf16_t* __restrict__ h1, const float* __restrict__ b1, int N)
{
    int wid = (blockIdx.x * 256 + threadIdx.x) >> 6;
    int lane = threadIdx.x & 63;
    int eslot = lane >> 4;       // 0..3
    int cg = lane & 15;          // cols [cg*4, cg*4+4)
    if (wid >= N) return;
    int eraw = csr[(size_t)wid * CAPN + lane];   // whole row, coalesced, no deps
    int d = cnt[wid];                            // parallel with eraw
    size_t o = (size_t)wid * 64 + cg * 4;
    uint2 su;
    float4 bb;
    if (eslot == 0) {
        su = *(const uint2*)(selfo + o);
        bb = *(const float4*)(b1 + cg * 4);
    }
    d = min(d, CAPN);
    float ax = 0.f, ay = 0.f, az = 0.f, aw = 0.f;
    if (d > 0) {
        int dm1 = d - 1;
#define G64_ACC(r, m)                                                      \
        {                                                                  \
            floatx2 p_ = __builtin_amdgcn_cvt_pk_f32_fp8((int)(r), false); \
            floatx2 q_ = __builtin_amdgcn_cvt_pk_f32_fp8((int)(r), true);  \
            ax += (m) * p_.x; ay += (m) * p_.y;                            \
            az += (m) * q_.x; aw += (m) * q_.y;                            \
        }
#define G64_BATCH(KN)                                                      \
        {                                                                  \
            int ss[KN];                                                    \
            float mk[KN];                                                  \
            unsigned rr[KN];                                               \
            _Pragma("unroll")                                              \
            for (int k = 0; k < KN; ++k) {                                 \
                int i = eslot + 4 * k;                                     \
                int idx = i > dm1 ? dm1 : i;                               \
                mk[k] = (i <= dm1) ? 1.f : 0.f;                            \
                ss[k] = __shfl(eraw, idx);                                 \
            }                                                              \
            _Pragma("unroll")                                              \
            for (int k = 0; k < KN; ++k)                                   \
                rr[k] = *(const unsigned*)(t1 + (size_t)ss[k] * 64 + cg * 4); \
            _Pragma("unroll")                                              \
            for (int k = 0; k < KN; ++k) G64_ACC(rr[k], mk[k]);            \
        }
        if (d <= 16) {
            G64_BATCH(4)
        } else if (d <= 32) {
            G64_BATCH(8)
        } else {
            G64_BATCH(16)   // rare (P[d>32] ~ 1e-4): full row, still depth 2
        }
#undef G64_BATCH
#undef G64_ACC
        ax += __shfl_xor(ax, 16); ay += __shfl_xor(ay, 16);
        az += __shfl_xor(az, 16); aw += __shfl_xor(aw, 16);
        ax += __shfl_xor(ax, 32); ay += __shfl_xor(ay, 32);
        az += __shfl_xor(az, 32); aw += __shfl_xor(aw, 32);
    }
    if (eslot == 0) {
        float inv = 1.f / fmaxf((float)d, 1.f);
        float rx = fmaxf(bfbits2f(su.x & 0xffff) + ax * inv + bb.x, 0.f);
        float ry = fmaxf(bfbits2f(su.x >> 16)    + ay * inv + bb.y, 0.f);
        float rz = fmaxf(bfbits2f(su.y & 0xffff) + az * inv + bb.z, 0.f);
        float rw = fmaxf(bfbits2f(su.y >> 16)    + aw * inv + bb.w, 0.f);
        uint2 pk;
        pk.x = pack2(rx, ry);
        pk.y = pack2(rz, rw);
        *(uint2*)(h1 + o) = pk;
    }
}

// ---------------- GEMM2: h1(bf16) [N,64] x [64,32] -> out(self) [N,16] f32, t2 [N,16] bf16 ----------------
__global__ __launch_bounds__(256) void gemm2_kernel(
    const bf16_t* __restrict__ h1, const float* __restrict__ Ws,
    const float* __restrict__ Wn, float* __restrict__ outp,
    bf16_t* __restrict__ t2, int N)
{
    __shared__ float Wc[64 * 32];    // 8 KB
    __shared__ float xs[128 * 65];   // 33.3 KB
    int t = threadIdx.x;
    int node0 = blockIdx.x * 128;

    for (int idx = t; idx < 64 * 32; idx += 256) {
        int k = idx >> 5, c = idx & 31;
        Wc[idx] = (c < 16) ? Ws[k * 16 + c] : Wn[k * 16 + (c - 16)];
    }
    for (int idx = t; idx < 128 * 8; idx += 256) {
        int row = idx >> 3, c8 = idx & 7;
        int node = node0 + row;
        float* p = &xs[row * 65 + c8 * 8];
        if (node < N) {
            uint4 u = *(const uint4*)(h1 + (size_t)node * 64 + c8 * 8);
            p[0] = bfbits2f(u.x & 0xffff); p[1] = bfbits2f(u.x >> 16);
            p[2] = bfbits2f(u.y & 0xffff); p[3] = bfbits2f(u.y >> 16);
            p[4] = bfbits2f(u.z & 0xffff); p[5] = bfbits2f(u.z >> 16);
            p[6] = bfbits2f(u.w & 0xffff); p[7] = bfbits2f(u.w >> 16);
        } else {
            for (int qq = 0; qq < 8; ++qq) p[qq] = 0.f;
        }
    }
    __syncthreads();

    int m = t & 31;
    int g = t >> 5;            // 8 col-groups of 4
    float acc[4][4];
#pragma unroll
    for (int j = 0; j < 4; ++j)
#pragma unroll
        for (int c = 0; c < 4; ++c) acc[j][c] = 0.f;

    for (int k = 0; k < 64; ++k) {
        float w[4];
        const float* wp = &Wc[k * 32 + g * 4];
#pragma unroll
        for (int c = 0; c < 4; ++c) w[c] = wp[c];
        float a0 = xs[m * 65 + k];
        float a1 = xs[(m + 32) * 65 + k];
        float a2 = xs[(m + 64) * 65 + k];
        float a3 = xs[(m + 96) * 65 + k];
#pragma unroll
        for (int c = 0; c < 4; ++c) {
            acc[0][c] += a0 * w[c];
            acc[1][c] += a1 * w[c];
            acc[2][c] += a2 * w[c];
            acc[3][c] += a3 * w[c];
        }
    }
#pragma unroll
    for (int j = 0; j < 4; ++j) {
        int node = node0 + m + 32 * j;
        if (node < N) {
            if (g < 4) {
                *(float4*)(outp + (size_t)node * 16 + g * 4) =
                    make_float4(acc[j][0], acc[j][1], acc[j][2], acc[j][3]);
            } else {
                uint2 pk;
                pk.x = pack2(acc[j][0], acc[j][1]);
                pk.y = pack2(acc[j][2], acc[j][3]);
                *(uint2*)(t2 + (size_t)node * 16 + (g - 4) * 4) = pk;
            }
        }
    }
}

// ---------------- gather16: out += (sum t2[src])/deg + b2 ----------------
// one wave per node; lane = (eslot 0..7, c2 0..7): 8 edge slots x 8 col-pairs.
__global__ __launch_bounds__(256) void gather16_kernel(
    const int* __restrict__ csr, const int* __restrict__ cnt,
    const bf16_t* __restrict__ t2,
    float* __restrict__ outp, const float* __restrict__ b2, int N)
{
    int wid = (blockIdx.x * 256 + threadIdx.x) >> 6;
    int lane = threadIdx.x & 63;
    int eslot = lane >> 3;       // 0..7
    int c2 = lane & 7;           // cols [c2*2, c2*2+2)
    if (wid >= N) return;
    int eraw = csr[(size_t)wid * CAPN + lane];   // whole row, coalesced
    int d = cnt[wid];
    // hoist epilogue operands early (RMW of outp + bias)
    size_t o = (size_t)wid * 16 + c2 * 2;
    float2 oo = make_float2(0.f, 0.f), bbv = make_float2(0.f, 0.f);
    if (eslot == 0) {
        oo = *(const float2*)(outp + o);
        bbv = *(const float2*)(b2 + c2 * 2);
    }
    d = min(d, CAPN);
    float a0 = 0.f, a1 = 0.f;
    if (d > 0) {
        int dm1 = d - 1;
#define G16_BATCH(KN)                                                      \
        {                                                                  \
            int ss[KN]; float mk[KN]; unsigned uu[KN];                     \
            _Pragma("unroll")                                              \
            for (int k = 0; k < KN; ++k) {                                 \
                int i = eslot + 8 * k;                                     \
                int idx = i > dm1 ? dm1 : i;                               \
                mk[k] = (i <= dm1) ? 1.f : 0.f;                            \
                ss[k] = __shfl(eraw, idx);                                 \
            }                                                              \
            _Pragma("unroll")                                              \
            for (int k = 0; k < KN; ++k)                                   \
                uu[k] = *(const unsigned*)(t2 + (size_t)ss[k] * 16 + c2 * 2); \
            _Pragma("unroll")                                              \
            for (int k = 0; k < KN; ++k) {                                 \
                a0 += mk[k] * bfbits2f(uu[k] & 0xffff);                    \
                a1 += mk[k] * bfbits2f(uu[k] >> 16);                       \
            }                                                              \
        }
        if (d <= 16) {
            G16_BATCH(2)
        } else if (d <= 32) {
            G16_BATCH(4)
        } else {
            G16_BATCH(8)
        }
#undef G16_BATCH
        a0 += __shfl_xor(a0, 8);  a1 += __shfl_xor(a1, 8);
        a0 += __shfl_xor(a0, 16); a1 += __shfl_xor(a1, 16);
        a0 += __shfl_xor(a0, 32); a1 += __shfl_xor(a1, 32);
    }
    if (eslot == 0) {
        float inv = 1.f / fmaxf((float)d, 1.f);
        float2 r;
        r.x = oo.x + a0 * inv + bbv.x;
        r.y = oo.y + a1 * inv + bbv.y;
        *(float2*)(outp + o) = r;
    }
}

extern "C" void kernel_launch(void* const* d_in, const int* in_sizes, int n_in,
                              void* d_out, int out_size, void* d_ws, size_t ws_size,
                              hipStream_t stream) {
    const float* x   = (const float*)d_in[0];
    const int*   src = (const int*)d_in[1];
    const int*   dst = (const int*)d_in[2];
    const float* Ws1 = (const float*)d_in[3];
    const float* Wn1 = (const float*)d_in[4];
    const float* b1  = (const float*)d_in[5];
    const float* Ws2 = (const float*)d_in[6];
    const float* Wn2 = (const float*)d_in[7];
    const float* b2  = (const float*)d_in[8];
    float* outp = (float*)d_out;

    const int N = in_sizes[0] / FEATS;   // 50000
    const int E = in_sizes[1];           // 800000
    const int B = (N + 255) / 256;       // buckets (196) — must be <= 256
    const int NBP = (E + 256 * EPT - 1) / (256 * EPT);   // partition blocks (196)
    const int NBG = (N + 127) / 128;                     // gemm1 blocks (391)

    // workspace (nothing pre-zeroed): blkcnt[NBP*256] | epart[B*NBP*CAPB] |
    //   cnt[N] | csr[N*CAPN] | selfo bf16[N*64] | t1 fp8[N*64] | h1 bf16[N*64] |
    //   t2 bf16[N*16]
    char* p = (char*)d_ws;
    auto align16 = [](char* q) { return (char*)(((size_t)q + 15) & ~(size_t)15); };
    int* blkcnt        = (int*)p;                  p = (char*)(blkcnt + (size_t)NBP * 256);
    int* epart         = (int*)align16(p);         p = (char*)(epart + (size_t)B * NBP * CAPB);
    int* cnt           = (int*)align16(p);         p = (char*)(cnt + N);
    int* csr           = (int*)align16(p);         p = (char*)(csr + (size_t)N * CAPN);
    bf16_t* selfo      = (bf16_t*)align16(p);      p = (char*)(selfo + (size_t)N * 64);
    unsigned char* t1  = (unsigned char*)align16(p); p = (char*)(t1 + (size_t)N * 64);
    bf16_t* h1         = (bf16_t*)align16(p);      p = (char*)(h1 + (size_t)N * 64);
    bf16_t* t2         = (bf16_t*)align16(p);

    fused_pg_kernel<<<NBP + NBG, 256, 0, stream>>>(
        src, dst, blkcnt, epart, E, x, Ws1, Wn1, selfo, t1, N, NBP);
    buildcsr_kernel<<<B, 256, 0, stream>>>(epart, blkcnt, cnt, csr, N, NBP);

    gather64_kernel<<<((size_t)N * 64 + 255) / 256, 256, 0, stream>>>(
        csr, cnt, t1, selfo, h1, b1, N);
    gemm2_kernel<<<(N + 127) / 128, 256, 0, stream>>>(h1, Ws2, Wn2, outp, t2, N);
    gather16_kernel<<<((size_t)N * 64 + 255) / 256, 256, 0, stream>>>(
        csr, cnt, t2, outp, b2, N);
}

// Round 10
// 156.878 us; speedup vs baseline: 1.3893x; 1.0210x over previous
//
#include <hip/hip_runtime.h>
#include <hip/hip_bf16.h>
#include <cstring>

// GraphSAGE 2-layer, CSR-gather formulation (no float atomics).
//   h1 = relu(x@Ws1 + mean_agg(x)@Wn1 + b1)
//   out = h1@Ws2 + mean_agg(h1)@Wn2 + b2
// mean_agg(h)@W == mean_agg(h@W): project first, then aggregate projected rows.
// R23: R17 base (proven 152.5us) with three conservative edits:
//  (1) partition -> own lean kernel; gemm1+buildcsr CO-DISPATCHED (independent:
//      x->t1/selfo vs epart->csr). buildcsr's latency-bound scan hides under
//      gemm1's VALU instead of running serial-alone. Still 6 dispatches, but
//      serial chain is one kernel shorter.
//  (2) buildcsr 4-way sub-bucket split: 784 blocks, each owns 64 nodes
//      EXCLUSIVELY (no cross-block csr/cnt line sharing -> R20's cross-XCD
//      ping-pong impossible). Cost: 4x streaming epart re-read (~10MB, trivial).
//  (3) csr as ushort (src < 50000 < 65536): halves csr writes and both
//      gathers' row loads (256B -> 128B per wave).
// t1 fp8 e4m3 (3.2 MB, L2-resident gather table); selfo/t2 bf16; fp32 acc.
// Closed experiment families:
//  R9:  LDS float-atomic aggregation -> 356 us disaster (serialized RMW).
//  R11: gather byte-shrink (fp8) -> small win; gathers are L2-hit LATENCY bound.
//  R13: wide-load instr-rate reduction -> neutral (confirms latency-bound).
//  R14: per-node in-wave gemm2 fusion -> regression (destroys W-tile reuse).
//  R15: fixed-depth predicated gathers -> small win (-4.4us).
//  R16: direct-slot CSR scatter -> +24us (random-line 4B writes, 56.7MB WRITE).
//  R17: bucket partition + single-pass fixed-cap CSR build -> 152.5us (BEST).
//  R18: cooperative mega-kernel -> 483.7us (grid.sync flushes 8 XCD L2s).
//  R19: gather+gemm2 block fusion -> 96us alone (node serialization killed TLP).
//  R20: cross-block global-atomic buildcsr -> +7.8us (cross-XCD line ping-pong).
//  R21: gemm2-into-gather fusion -> 87us alone (aggregated 64-dim h1, 6.4MB
//       table > 4MiB per-XCD L2). Aggregate in the PROJECTED space, tables <4MiB.
//  R22: segment partition/buildcsr -> +7.7us (partial-line segment writes).
//       R17's bucket-contiguous epart runs + tiny memset is the best front-end.

#define FEATS 64
#define CLS   16
#define EPT   16      // edges/thread in partition role (4096 edges/block)
#define CAP   5120    // bucket capacity; mean 4081 edges/bucket, 16 sigma margin
#define CAPN  64      // per-node CSR row capacity (Poisson(16): P[d>64]~1e-18)

typedef unsigned short bf16_t;
typedef float floatx2 __attribute__((ext_vector_type(2)));

__device__ __forceinline__ float bfbits2f(unsigned lo16) {
    unsigned v = lo16 << 16;
    float f;
    __builtin_memcpy(&f, &v, 4);
    return f;
}
__device__ __forceinline__ bf16_t f2bf(float f) {
    unsigned u;
    __builtin_memcpy(&u, &f, 4);
    u = (u + 0x7FFFu + ((u >> 16) & 1u)) >> 16;   // round-to-nearest-even
    return (bf16_t)u;
}
__device__ __forceinline__ unsigned pack2(float a, float b) {
    return (unsigned)f2bf(a) | ((unsigned)f2bf(b) << 16);
}
// pack 4 f32 -> 4 fp8 e4m3 in one dword (HW cvt, RNE)
__device__ __forceinline__ unsigned pack4_fp8(float a, float b, float c, float d) {
    int q = __builtin_amdgcn_cvt_pk_fp8_f32(a, b, 0, false);
    q = __builtin_amdgcn_cvt_pk_fp8_f32(c, d, q, true);
    return (unsigned)q;
}

// ---------------- partition: bucket-coalesced edge scatter (R17-proven, lean LDS) ----------------
__global__ __launch_bounds__(256) void partition_kernel(
    const int* __restrict__ src, const int* __restrict__ dst,
    int* __restrict__ bucket_cnt, int* __restrict__ epart, int E)
{
    __shared__ int hist[256];
    __shared__ int base[256];
    int t = threadIdx.x;
    int e0 = blockIdx.x * (256 * EPT);
    hist[t] = 0;
    __syncthreads();
    int pk[EPT];
    int bk[EPT];
#pragma unroll
    for (int j = 0; j < EPT; ++j) {
        int e = e0 + j * 256 + t;
        if (e < E) {
            int d = dst[e];
            pk[j] = (src[e] << 8) | (d & 255);
            bk[j] = d >> 8;
            atomicAdd(&hist[bk[j]], 1);
        } else bk[j] = -1;
    }
    __syncthreads();
    int c = hist[t];
    if (c) base[t] = atomicAdd(&bucket_cnt[t], c);
    hist[t] = 0;
    __syncthreads();
#pragma unroll
    for (int j = 0; j < EPT; ++j) {
        if (bk[j] >= 0) {
            int r = atomicAdd(&hist[bk[j]], 1);
            epart[bk[j] * CAP + base[bk[j]] + r] = pk[j];
        }
    }
}

// ---------------- fused: GEMM1 (blocks [0,nbg)) + buildcsr (blocks [nbg, nbg+4B)) ----------------
// gemm1 first (long-running, resident), buildcsr blocks stream in underneath.
// buildcsr: 4 sub-blocks per bucket; sub-block q owns nodes ln in [q*64,q*64+64)
// EXCLUSIVELY (no cross-block sharing). Scans whole bucket, filters by quarter.
__global__ __launch_bounds__(256) void fused_bg_kernel(
    const int* __restrict__ epart, const int* __restrict__ bucket_cnt,
    int* __restrict__ cnt, unsigned short* __restrict__ csr,
    const float* __restrict__ x, const float* __restrict__ Ws,
    const float* __restrict__ Wn, bf16_t* __restrict__ selfo,
    unsigned char* __restrict__ t1, int N, int nbg)
{
    __shared__ float smem[16512];   // 66 KB: gemm1 Wc[8192]+xs[8320]; buildcsr cnt
    int t = threadIdx.x;

    if ((int)blockIdx.x >= nbg) {
        // ---- buildcsr role ----
        int u = (int)blockIdx.x - nbg;
        int b = u >> 2;              // bucket
        int q = u & 3;               // quarter: nodes [q*64, q*64+64)
        int* c = (int*)smem;         // 64 counters
        if (t < 64) c[t] = 0;
        __syncthreads();
        int ebeg = b * CAP;
        int ecnt = bucket_cnt[b];
        for (int e = t; e < ecnt; e += 256) {
            int pk = epart[ebeg + e];
            int ln = pk & 255;
            if ((ln >> 6) == q) {
                int r = atomicAdd(&c[ln & 63], 1);
                if (r < CAPN)
                    csr[(size_t)(b * 256 + ln) * CAPN + r] = (unsigned short)(pk >> 8);
            }
        }
        __syncthreads();
        int node = b * 256 + q * 64 + t;
        if (t < 64 && node < N) cnt[node] = c[t];
        return;
    }

    // ---- gemm1 role ----
    float* Wc = smem;           // 64*128
    float* xs = smem + 8192;    // 128*65
    int node0 = (int)blockIdx.x * 128;

    for (int idx = t; idx < 64 * 128; idx += 256) {
        int k = idx >> 7, c = idx & 127;
        Wc[idx] = (c < 64) ? Ws[k * 64 + c] : Wn[k * 64 + (c - 64)];
    }
    for (int idx = t; idx < 128 * 16; idx += 256) {
        int row = idx >> 4, c4 = idx & 15;
        int node = node0 + row;
        float4 v = (node < N) ? ((const float4*)(x + (size_t)node * 64))[c4]
                              : make_float4(0.f, 0.f, 0.f, 0.f);
        float* p = &xs[row * 65 + c4 * 4];
        p[0] = v.x; p[1] = v.y; p[2] = v.z; p[3] = v.w;
    }
    __syncthreads();

    int m = t & 31;
    int g = t >> 5;            // 8 col-groups of 16
    float acc[4][16];
#pragma unroll
    for (int j = 0; j < 4; ++j)
#pragma unroll
        for (int c = 0; c < 16; ++c) acc[j][c] = 0.f;

    for (int k = 0; k < 64; ++k) {
        float w[16];
        const float* wp = &Wc[k * 128 + g * 16];
#pragma unroll
        for (int c = 0; c < 16; ++c) w[c] = wp[c];
        float a0 = xs[m * 65 + k];
        float a1 = xs[(m + 32) * 65 + k];
        float a2 = xs[(m + 64) * 65 + k];
        float a3 = xs[(m + 96) * 65 + k];
#pragma unroll
        for (int c = 0; c < 16; ++c) {
            acc[0][c] += a0 * w[c];
            acc[1][c] += a1 * w[c];
            acc[2][c] += a2 * w[c];
            acc[3][c] += a3 * w[c];
        }
    }
#pragma unroll
    for (int j = 0; j < 4; ++j) {
        int node = node0 + m + 32 * j;
        if (node < N) {
            if (g < 4) {
                bf16_t* dstp = selfo + (size_t)node * 64 + g * 16;
                uint4 p0, p1;
                p0.x = pack2(acc[j][0],  acc[j][1]);  p0.y = pack2(acc[j][2],  acc[j][3]);
                p0.z = pack2(acc[j][4],  acc[j][5]);  p0.w = pack2(acc[j][6],  acc[j][7]);
                p1.x = pack2(acc[j][8],  acc[j][9]);  p1.y = pack2(acc[j][10], acc[j][11]);
                p1.z = pack2(acc[j][12], acc[j][13]); p1.w = pack2(acc[j][14], acc[j][15]);
                *(uint4*)(dstp) = p0;
                *(uint4*)(dstp + 8) = p1;
            } else {
                unsigned char* dstp = t1 + (size_t)node * 64 + (g - 4) * 16;
                uint4 qv;
                qv.x = pack4_fp8(acc[j][0],  acc[j][1],  acc[j][2],  acc[j][3]);
                qv.y = pack4_fp8(acc[j][4],  acc[j][5],  acc[j][6],  acc[j][7]);
                qv.z = pack4_fp8(acc[j][8],  acc[j][9],  acc[j][10], acc[j][11]);
                qv.w = pack4_fp8(acc[j][12], acc[j][13], acc[j][14], acc[j][15]);
                *(uint4*)(dstp) = qv;
            }
        }
    }
}

// ---------------- gather64: h1 = relu(selfo + (sum t1[src])/deg + b1) ----------------
// one wave per node; lane = (eslot, cg): 4 edge slots x 16 col-groups (dword = 4 fp8).
// Row base computable (wid*64): ushort csr row load (128B/wave) + cnt load both
// issue at cycle 0; edge select via __shfl with d-clamped index; depth 2.
__global__ __launch_bounds__(256) void gather64_kernel(
    const unsigned short* __restrict__ csr, const int* __restrict__ cnt,
    const unsigned char* __restrict__ t1, const bf16_t* __restrict__ selfo,
    bf16_t* __restrict__ h1, const float* __restrict__ b1, int N)
{
    int wid = (blockIdx.x * 256 + threadIdx.x) >> 6;
    int lane = threadIdx.x & 63;
    int eslot = lane >> 4;       // 0..3
    int cg = lane & 15;          // cols [cg*4, cg*4+4)
    if (wid >= N) return;
    int eraw = (int)csr[(size_t)wid * CAPN + lane];   // whole row, coalesced
    int d = cnt[wid];                                 // parallel with eraw
    size_t o = (size_t)wid * 64 + cg * 4;
    uint2 su;
    float4 bb;
    if (eslot == 0) {
        su = *(const uint2*)(selfo + o);
        bb = *(const float4*)(b1 + cg * 4);
    }
    d = min(d, CAPN);
    float ax = 0.f, ay = 0.f, az = 0.f, aw = 0.f;
    if (d > 0) {
        int dm1 = d - 1;
#define G64_ACC(r, m)                                                      \
        {                                                                  \
            floatx2 p_ = __builtin_amdgcn_cvt_pk_f32_fp8((int)(r), false); \
            floatx2 q_ = __builtin_amdgcn_cvt_pk_f32_fp8((int)(r), true);  \
            ax += (m) * p_.x; ay += (m) * p_.y;                            \
            az += (m) * q_.x; aw += (m) * q_.y;                            \
        }
#define G64_BATCH(KN)                                                      \
        {                                                                  \
            int ss[KN];                                                    \
            float mk[KN];                                                  \
            unsigned rr[KN];                                               \
            _Pragma("unroll")                                              \
            for (int k = 0; k < KN; ++k) {                                 \
                int i = eslot + 4 * k;                                     \
                int idx = i > dm1 ? dm1 : i;                               \
                mk[k] = (i <= dm1) ? 1.f : 0.f;                            \
                ss[k] = __shfl(eraw, idx);                                 \
            }                                                              \
            _Pragma("unroll")                                              \
            for (int k = 0; k < KN; ++k)                                   \
                rr[k] = *(const unsigned*)(t1 + (size_t)ss[k] * 64 + cg * 4); \
            _Pragma("unroll")                                              \
            for (int k = 0; k < KN; ++k) G64_ACC(rr[k], mk[k]);            \
        }
        if (d <= 16) {
            G64_BATCH(4)
        } else if (d <= 32) {
            G64_BATCH(8)
        } else {
            G64_BATCH(16)   // rare (P[d>32] ~ 1e-4): full row, still depth 2
        }
#undef G64_BATCH
#undef G64_ACC
        ax += __shfl_xor(ax, 16); ay += __shfl_xor(ay, 16);
        az += __shfl_xor(az, 16); aw += __shfl_xor(aw, 16);
        ax += __shfl_xor(ax, 32); ay += __shfl_xor(ay, 32);
        az += __shfl_xor(az, 32); aw += __shfl_xor(aw, 32);
    }
    if (eslot == 0) {
        float inv = 1.f / fmaxf((float)d, 1.f);
        float rx = fmaxf(bfbits2f(su.x & 0xffff) + ax * inv + bb.x, 0.f);
        float ry = fmaxf(bfbits2f(su.x >> 16)    + ay * inv + bb.y, 0.f);
        float rz = fmaxf(bfbits2f(su.y & 0xffff) + az * inv + bb.z, 0.f);
        float rw = fmaxf(bfbits2f(su.y >> 16)    + aw * inv + bb.w, 0.f);
        uint2 pk;
        pk.x = pack2(rx, ry);
        pk.y = pack2(rz, rw);
        *(uint2*)(h1 + o) = pk;
    }
}

// ---------------- GEMM2: h1(bf16) [N,64] x [64,32] -> out(self) [N,16] f32, t2 [N,16] bf16 ----------------
__global__ __launch_bounds__(256) void gemm2_kernel(
    const bf16_t* __restrict__ h1, const float* __restrict__ Ws,
    const float* __restrict__ Wn, float* __restrict__ outp,
    bf16_t* __restrict__ t2, int N)
{
    __shared__ float Wc[64 * 32];    // 8 KB
    __shared__ float xs[128 * 65];   // 33.3 KB
    int t = threadIdx.x;
    int node0 = blockIdx.x * 128;

    for (int idx = t; idx < 64 * 32; idx += 256) {
        int k = idx >> 5, c = idx & 31;
        Wc[idx] = (c < 16) ? Ws[k * 16 + c] : Wn[k * 16 + (c - 16)];
    }
    for (int idx = t; idx < 128 * 8; idx += 256) {
        int row = idx >> 3, c8 = idx & 7;
        int node = node0 + row;
        float* p = &xs[row * 65 + c8 * 8];
        if (node < N) {
            uint4 u = *(const uint4*)(h1 + (size_t)node * 64 + c8 * 8);
            p[0] = bfbits2f(u.x & 0xffff); p[1] = bfbits2f(u.x >> 16);
            p[2] = bfbits2f(u.y & 0xffff); p[3] = bfbits2f(u.y >> 16);
            p[4] = bfbits2f(u.z & 0xffff); p[5] = bfbits2f(u.z >> 16);
            p[6] = bfbits2f(u.w & 0xffff); p[7] = bfbits2f(u.w >> 16);
        } else {
            for (int qq = 0; qq < 8; ++qq) p[qq] = 0.f;
        }
    }
    __syncthreads();

    int m = t & 31;
    int g = t >> 5;            // 8 col-groups of 4
    float acc[4][4];
#pragma unroll
    for (int j = 0; j < 4; ++j)
#pragma unroll
        for (int c = 0; c < 4; ++c) acc[j][c] = 0.f;

    for (int k = 0; k < 64; ++k) {
        float w[4];
        const float* wp = &Wc[k * 32 + g * 4];
#pragma unroll
        for (int c = 0; c < 4; ++c) w[c] = wp[c];
        float a0 = xs[m * 65 + k];
        float a1 = xs[(m + 32) * 65 + k];
        float a2 = xs[(m + 64) * 65 + k];
        float a3 = xs[(m + 96) * 65 + k];
#pragma unroll
        for (int c = 0; c < 4; ++c) {
            acc[0][c] += a0 * w[c];
            acc[1][c] += a1 * w[c];
            acc[2][c] += a2 * w[c];
            acc[3][c] += a3 * w[c];
        }
    }
#pragma unroll
    for (int j = 0; j < 4; ++j) {
        int node = node0 + m + 32 * j;
        if (node < N) {
            if (g < 4) {
                *(float4*)(outp + (size_t)node * 16 + g * 4) =
                    make_float4(acc[j][0], acc[j][1], acc[j][2], acc[j][3]);
            } else {
                uint2 pk;
                pk.x = pack2(acc[j][0], acc[j][1]);
                pk.y = pack2(acc[j][2], acc[j][3]);
                *(uint2*)(t2 + (size_t)node * 16 + (g - 4) * 4) = pk;
            }
        }
    }
}

// ---------------- gather16: out += (sum t2[src])/deg + b2 ----------------
// one wave per node; lane = (eslot 0..7, c2 0..7): 8 edge slots x 8 col-pairs.
__global__ __launch_bounds__(256) void gather16_kernel(
    const unsigned short* __restrict__ csr, const int* __restrict__ cnt,
    const bf16_t* __restrict__ t2,
    float* __restrict__ outp, const float* __restrict__ b2, int N)
{
    int wid = (blockIdx.x * 256 + threadIdx.x) >> 6;
    int lane = threadIdx.x & 63;
    int eslot = lane >> 3;       // 0..7
    int c2 = lane & 7;           // cols [c2*2, c2*2+2)
    if (wid >= N) return;
    int eraw = (int)csr[(size_t)wid * CAPN + lane];   // whole row, coalesced
    int d = cnt[wid];
    // hoist epilogue operands early (RMW of outp + bias)
    size_t o = (size_t)wid * 16 + c2 * 2;
    float2 oo = make_float2(0.f, 0.f), bbv = make_float2(0.f, 0.f);
    if (eslot == 0) {
        oo = *(const float2*)(outp + o);
        bbv = *(const float2*)(b2 + c2 * 2);
    }
    d = min(d, CAPN);
    float a0 = 0.f, a1 = 0.f;
    if (d > 0) {
        int dm1 = d - 1;
#define G16_BATCH(KN)                                                      \
        {                                                                  \
            int ss[KN]; float mk[KN]; unsigned uu[KN];                     \
            _Pragma("unroll")                                              \
            for (int k = 0; k < KN; ++k) {                                 \
                int i = eslot + 8 * k;                                     \
                int idx = i > dm1 ? dm1 : i;                               \
                mk[k] = (i <= dm1) ? 1.f : 0.f;                            \
                ss[k] = __shfl(eraw, idx);                                 \
            }                                                              \
            _Pragma("unroll")                                              \
            for (int k = 0; k < KN; ++k)                                   \
                uu[k] = *(const unsigned*)(t2 + (size_t)ss[k] * 16 + c2 * 2); \
            _Pragma("unroll")                                              \
            for (int k = 0; k < KN; ++k) {                                 \
                a0 += mk[k] * bfbits2f(uu[k] & 0xffff);                    \
                a1 += mk[k] * bfbits2f(uu[k] >> 16);                       \
            }                                                              \
        }
        if (d <= 16) {
            G16_BATCH(2)
        } else if (d <= 32) {
            G16_BATCH(4)
        } else {
            G16_BATCH(8)
        }
#undef G16_BATCH
        a0 += __shfl_xor(a0, 8);  a1 += __shfl_xor(a1, 8);
        a0 += __shfl_xor(a0, 16); a1 += __shfl_xor(a1, 16);
        a0 += __shfl_xor(a0, 32); a1 += __shfl_xor(a1, 32);
    }
    if (eslot == 0) {
        float inv = 1.f / fmaxf((float)d, 1.f);
        float2 r;
        r.x = oo.x + a0 * inv + bbv.x;
        r.y = oo.y + a1 * inv + bbv.y;
        *(float2*)(outp + o) = r;
    }
}

extern "C" void kernel_launch(void* const* d_in, const int* in_sizes, int n_in,
                              void* d_out, int out_size, void* d_ws, size_t ws_size,
                              hipStream_t stream) {
    const float* x   = (const float*)d_in[0];
    const int*   src = (const int*)d_in[1];
    const int*   dst = (const int*)d_in[2];
    const float* Ws1 = (const float*)d_in[3];
    const float* Wn1 = (const float*)d_in[4];
    const float* b1  = (const float*)d_in[5];
    const float* Ws2 = (const float*)d_in[6];
    const float* Wn2 = (const float*)d_in[7];
    const float* b2  = (const float*)d_in[8];
    float* outp = (float*)d_out;

    const int N = in_sizes[0] / FEATS;   // 50000
    const int E = in_sizes[1];           // 800000
    const int B = (N + 255) / 256;       // buckets (196) — must be <= 256
    const int NBP = (E + 256 * EPT - 1) / (256 * EPT);   // partition blocks (196)
    const int NBG = (N + 127) / 128;                     // gemm1 blocks (391)

    // workspace: bucket_cnt[256] | epart[B*CAP] | cnt[N] | csr u16[N*CAPN] |
    //            selfo bf16[N*64] | t1 fp8[N*64] | h1 bf16[N*64] | t2 bf16[N*16]
    char* p = (char*)d_ws;
    auto align16 = [](char* q) { return (char*)(((size_t)q + 15) & ~(size_t)15); };
    int* bucket_cnt    = (int*)p;                  p = (char*)(bucket_cnt + 256);
    int* epart         = (int*)p;                  p = (char*)(epart + (size_t)B * CAP);
    int* cnt           = (int*)align16(p);         p = (char*)(cnt + N);
    unsigned short* csr = (unsigned short*)align16(p); p = (char*)(csr + (size_t)N * CAPN);
    bf16_t* selfo      = (bf16_t*)align16(p);      p = (char*)(selfo + (size_t)N * 64);
    unsigned char* t1  = (unsigned char*)align16(p); p = (char*)(t1 + (size_t)N * 64);
    bf16_t* h1         = (bf16_t*)align16(p);      p = (char*)(h1 + (size_t)N * 64);
    bf16_t* t2         = (bf16_t*)align16(p);

    hipMemsetAsync(bucket_cnt, 0, 256 * sizeof(int), stream);

    partition_kernel<<<NBP, 256, 0, stream>>>(src, dst, bucket_cnt, epart, E);
    fused_bg_kernel<<<NBG + 4 * B, 256, 0, stream>>>(
        epart, bucket_cnt, cnt, csr, x, Ws1, Wn1, selfo, t1, N, NBG);

    gather64_kernel<<<((size_t)N * 64 + 255) / 256, 256, 0, stream>>>(
        csr, cnt, t1, selfo, h1, b1, N);
    gemm2_kernel<<<(N + 127) / 128, 256, 0, stream>>>(h1, Ws2, Wn2, outp, t2, N);
    gather16_kernel<<<((size_t)N * 64 + 255) / 256, 256, 0, stream>>>(
        csr, cnt, t2, outp, b2, N);
}

// Round 11
// 148.717 us; speedup vs baseline: 1.4655x; 1.0549x over previous
//
#include <hip/hip_runtime.h>
#include <hip/hip_bf16.h>
#include <cstring>

// GraphSAGE 2-layer, CSR-gather formulation (no float atomics).
//   h1 = relu(x@Ws1 + mean_agg(x)@Wn1 + b1)
//   out = h1@Ws2 + mean_agg(h1)@Wn2 + b2
// mean_agg(h)@W == mean_agg(h@W): project first, then aggregate projected rows.
// R24: R17 base (proven 152.5us best) + ONE lever: bf16 activation tiles in
//   LDS to raise gemm occupancy (cross-round ledger: fused_pg ~30us at 2
//   blocks/CU from 66KB LDS; gemm2 41.3KB at 3 blocks/CU).
//   gemm1 xs fp32->bf16 (stride 68: 8B-aligned stores, 2-way-free banks):
//     LDS 66->49KB -> 3 blocks/CU. x-rounding ~0.4% rel, < fp8-t1 error.
//   gemm2 xs: h1 is ALREADY bf16 -> raw ushort tile, zero added rounding:
//     LDS 41.3->24.9KB -> 6 blocks/CU.
//   Everything else R17-identical.
// t1 fp8 e4m3 (3.2 MB, L2-resident gather table); selfo/t2 bf16; fp32 acc.
// Closed experiment families:
//  R9:  LDS float-atomic aggregation -> 356 us disaster (serialized RMW).
//  R11: gather byte-shrink (fp8) -> small win; gathers are L2-hit LATENCY bound.
//  R13: wide-load instr-rate reduction -> neutral (confirms latency-bound).
//  R14: per-node in-wave gemm2 fusion -> regression (destroys W-tile reuse).
//  R15: fixed-depth predicated gathers -> small win (-4.4us).
//  R16: direct-slot CSR scatter -> +24us (random-line 4B writes, 56.7MB WRITE).
//  R17: bucket partition + single-pass fixed-cap CSR build -> 152.5us (BEST).
//  R18: cooperative mega-kernel -> 483.7us (grid.sync flushes 8 XCD L2s).
//  R19: gather+gemm2 block fusion -> 96us alone (node serialization killed TLP).
//  R20: cross-block global-atomic buildcsr -> +7.8us (cross-XCD line ping-pong).
//  R21: gemm2-into-gather fusion -> 87us alone (aggregate in PROJECTED space;
//       gather tables must stay < 4MiB per-XCD L2).
//  R22: segment partition/buildcsr -> +7.7us (partial-line segment writes).
//  R23: split-partition + 4-way buildcsr + ushort csr bundle -> +4.4us.
// Budget model (R16/R19/R21 subtraction, consistent): dur ~= 43us poison fill
//   (in timed region) + ~5us/gap x 5 + kernels ~80us (fused_pg ~30 dominant).

#define FEATS 64
#define CLS   16
#define EPT   16      // edges/thread in partition role (4096 edges/block)
#define CAP   5120    // bucket capacity; mean 4081 edges/bucket, 16 sigma margin
#define CAPN  64      // per-node CSR row capacity (Poisson(16): P[d>64]~1e-18)
#define XS_S  68      // xs tile stride in ushorts: 8B-aligned rows, 2-way banks

typedef unsigned short bf16_t;
typedef float floatx2 __attribute__((ext_vector_type(2)));

__device__ __forceinline__ float bfbits2f(unsigned lo16) {
    unsigned v = lo16 << 16;
    float f;
    __builtin_memcpy(&f, &v, 4);
    return f;
}
__device__ __forceinline__ bf16_t f2bf(float f) {
    unsigned u;
    __builtin_memcpy(&u, &f, 4);
    u = (u + 0x7FFFu + ((u >> 16) & 1u)) >> 16;   // round-to-nearest-even
    return (bf16_t)u;
}
__device__ __forceinline__ unsigned pack2(float a, float b) {
    return (unsigned)f2bf(a) | ((unsigned)f2bf(b) << 16);
}
// pack 4 f32 -> 4 fp8 e4m3 in one dword (HW cvt, RNE)
__device__ __forceinline__ unsigned pack4_fp8(float a, float b, float c, float d) {
    int q = __builtin_amdgcn_cvt_pk_fp8_f32(a, b, 0, false);
    q = __builtin_amdgcn_cvt_pk_fp8_f32(c, d, q, true);
    return (unsigned)q;
}

// ---------------- fused: partition (blocks [0,nbp)) + GEMM1 (blocks [nbp, nbp+nbg)) ----------------
__global__ __launch_bounds__(256) void fused_pg_kernel(
    const int* __restrict__ src, const int* __restrict__ dst,
    int* __restrict__ bucket_cnt, int* __restrict__ epart, int E,
    const float* __restrict__ x, const float* __restrict__ Ws,
    const float* __restrict__ Wn, bf16_t* __restrict__ selfo,
    unsigned char* __restrict__ t1, int N, int nbp)
{
    __shared__ float Wc[64 * 128];            // 32 KB (partition reuses as hist/base)
    __shared__ unsigned short xsu[128 * XS_S]; // 17 KB bf16 tile -> total 49KB, 3 blk/CU
    int t = threadIdx.x;

    if ((int)blockIdx.x < nbp) {
        // ---- partition role: bucket-coalesced edge scatter (R16 lesson) ----
        int* hist = (int*)Wc;
        int* base = hist + 256;
        int e0 = blockIdx.x * (256 * EPT);
        hist[t] = 0;
        __syncthreads();
        int pk[EPT];
        int bk[EPT];
#pragma unroll
        for (int j = 0; j < EPT; ++j) {
            int e = e0 + j * 256 + t;
            if (e < E) {
                int d = dst[e];
                pk[j] = (src[e] << 8) | (d & 255);
                bk[j] = d >> 8;
                atomicAdd(&hist[bk[j]], 1);
            } else bk[j] = -1;
        }
        __syncthreads();
        int c = hist[t];
        if (c) base[t] = atomicAdd(&bucket_cnt[t], c);
        hist[t] = 0;
        __syncthreads();
#pragma unroll
        for (int j = 0; j < EPT; ++j) {
            if (bk[j] >= 0) {
                int r = atomicAdd(&hist[bk[j]], 1);
                epart[bk[j] * CAP + base[bk[j]] + r] = pk[j];
            }
        }
        return;
    }

    // ---- gemm1 role ----
    int node0 = ((int)blockIdx.x - nbp) * 128;

    for (int idx = t; idx < 64 * 128; idx += 256) {
        int k = idx >> 7, c = idx & 127;
        Wc[idx] = (c < 64) ? Ws[k * 64 + c] : Wn[k * 64 + (c - 64)];
    }
    for (int idx = t; idx < 128 * 16; idx += 256) {
        int row = idx >> 4, c4 = idx & 15;
        int node = node0 + row;
        float4 v = (node < N) ? ((const float4*)(x + (size_t)node * 64))[c4]
                              : make_float4(0.f, 0.f, 0.f, 0.f);
        uint2 pk;
        pk.x = pack2(v.x, v.y);
        pk.y = pack2(v.z, v.w);
        *(uint2*)(xsu + row * XS_S + c4 * 4) = pk;   // byte off row*136+c4*8, 8B-aligned
    }
    __syncthreads();

    int m = t & 31;
    int g = t >> 5;            // 8 col-groups of 16
    float acc[4][16];
#pragma unroll
    for (int j = 0; j < 4; ++j)
#pragma unroll
        for (int c = 0; c < 16; ++c) acc[j][c] = 0.f;

    for (int k = 0; k < 64; ++k) {
        float w[16];
        const float* wp = &Wc[k * 128 + g * 16];
#pragma unroll
        for (int c = 0; c < 16; ++c) w[c] = wp[c];
        float a0 = bfbits2f(xsu[m * XS_S + k]);
        float a1 = bfbits2f(xsu[(m + 32) * XS_S + k]);
        float a2 = bfbits2f(xsu[(m + 64) * XS_S + k]);
        float a3 = bfbits2f(xsu[(m + 96) * XS_S + k]);
#pragma unroll
        for (int c = 0; c < 16; ++c) {
            acc[0][c] += a0 * w[c];
            acc[1][c] += a1 * w[c];
            acc[2][c] += a2 * w[c];
            acc[3][c] += a3 * w[c];
        }
    }
#pragma unroll
    for (int j = 0; j < 4; ++j) {
        int node = node0 + m + 32 * j;
        if (node < N) {
            if (g < 4) {
                bf16_t* dstp = selfo + (size_t)node * 64 + g * 16;
                uint4 p0, p1;
                p0.x = pack2(acc[j][0],  acc[j][1]);  p0.y = pack2(acc[j][2],  acc[j][3]);
                p0.z = pack2(acc[j][4],  acc[j][5]);  p0.w = pack2(acc[j][6],  acc[j][7]);
                p1.x = pack2(acc[j][8],  acc[j][9]);  p1.y = pack2(acc[j][10], acc[j][11]);
                p1.z = pack2(acc[j][12], acc[j][13]); p1.w = pack2(acc[j][14], acc[j][15]);
                *(uint4*)(dstp) = p0;
                *(uint4*)(dstp + 8) = p1;
            } else {
                unsigned char* dstp = t1 + (size_t)node * 64 + (g - 4) * 16;
                uint4 q;
                q.x = pack4_fp8(acc[j][0],  acc[j][1],  acc[j][2],  acc[j][3]);
                q.y = pack4_fp8(acc[j][4],  acc[j][5],  acc[j][6],  acc[j][7]);
                q.z = pack4_fp8(acc[j][8],  acc[j][9],  acc[j][10], acc[j][11]);
                q.w = pack4_fp8(acc[j][12], acc[j][13], acc[j][14], acc[j][15]);
                *(uint4*)(dstp) = q;
            }
        }
    }
}

// ---------------- single-pass bucket -> fixed-capacity CSR rows (R17-proven) ----------------
__global__ __launch_bounds__(256) void buildcsr_kernel(const int* __restrict__ epart,
                                                       const int* __restrict__ bucket_cnt,
                                                       int* __restrict__ cnt,
                                                       int* __restrict__ csr, int N) {
    __shared__ int c[256];
    int t = threadIdx.x;
    int b = blockIdx.x;
    int ebeg = b * CAP;
    int ecnt = bucket_cnt[b];
    c[t] = 0;
    __syncthreads();
    for (int e = t; e < ecnt; e += 256) {
        int pk = epart[ebeg + e];
        int ln = pk & 255;
        int r = atomicAdd(&c[ln], 1);
        if (r < CAPN) csr[(size_t)(b * 256 + ln) * CAPN + r] = pk >> 8;
    }
    __syncthreads();
    int node = b * 256 + t;
    if (node < N) cnt[node] = c[t];
}

// ---------------- gather64: h1 = relu(selfo + (sum t1[src])/deg + b1) ----------------
// one wave per node; lane = (eslot, cg): 4 edge slots x 16 col-groups (dword = 4 fp8).
// Row base computable (wid*64); edge select via __shfl; strict depth 2. (R17-proven.)
__global__ __launch_bounds__(256) void gather64_kernel(
    const int* __restrict__ csr, const int* __restrict__ cnt,
    const unsigned char* __restrict__ t1, const bf16_t* __restrict__ selfo,
    bf16_t* __restrict__ h1, const float* __restrict__ b1, int N)
{
    int wid = (blockIdx.x * 256 + threadIdx.x) >> 6;
    int lane = threadIdx.x & 63;
    int eslot = lane >> 4;       // 0..3
    int cg = lane & 15;          // cols [cg*4, cg*4+4)
    if (wid >= N) return;
    int eraw = csr[(size_t)wid * CAPN + lane];   // whole row, coalesced, no deps
    int d = cnt[wid];                            // parallel with eraw
    size_t o = (size_t)wid * 64 + cg * 4;
    uint2 su;
    float4 bb;
    if (eslot == 0) {
        su = *(const uint2*)(selfo + o);
        bb = *(const float4*)(b1 + cg * 4);
    }
    d = min(d, CAPN);
    float ax = 0.f, ay = 0.f, az = 0.f, aw = 0.f;
    if (d > 0) {
        int dm1 = d - 1;
#define G64_ACC(r, m)                                                      \
        {                                                                  \
            floatx2 p_ = __builtin_amdgcn_cvt_pk_f32_fp8((int)(r), false); \
            floatx2 q_ = __builtin_amdgcn_cvt_pk_f32_fp8((int)(r), true);  \
            ax += (m) * p_.x; ay += (m) * p_.y;                            \
            az += (m) * q_.x; aw += (m) * q_.y;                            \
        }
#define G64_BATCH(KN)                                                      \
        {                                                                  \
            int ss[KN];                                                    \
            float mk[KN];                                                  \
            unsigned rr[KN];                                               \
            _Pragma("unroll")                                              \
            for (int k = 0; k < KN; ++k) {                                 \
                int i = eslot + 4 * k;                                     \
                int idx = i > dm1 ? dm1 : i;                               \
                mk[k] = (i <= dm1) ? 1.f : 0.f;                            \
                ss[k] = __shfl(eraw, idx);                                 \
            }                                                              \
            _Pragma("unroll")                                              \
            for (int k = 0; k < KN; ++k)                                   \
                rr[k] = *(const unsigned*)(t1 + (size_t)ss[k] * 64 + cg * 4); \
            _Pragma("unroll")                                              \
            for (int k = 0; k < KN; ++k) G64_ACC(rr[k], mk[k]);            \
        }
        if (d <= 16) {
            G64_BATCH(4)
        } else if (d <= 32) {
            G64_BATCH(8)
        } else {
            G64_BATCH(16)   // rare (P[d>32] ~ 1e-4): full row, still depth 2
        }
#undef G64_BATCH
#undef G64_ACC
        ax += __shfl_xor(ax, 16); ay += __shfl_xor(ay, 16);
        az += __shfl_xor(az, 16); aw += __shfl_xor(aw, 16);
        ax += __shfl_xor(ax, 32); ay += __shfl_xor(ay, 32);
        az += __shfl_xor(az, 32); aw += __shfl_xor(aw, 32);
    }
    if (eslot == 0) {
        float inv = 1.f / fmaxf((float)d, 1.f);
        float rx = fmaxf(bfbits2f(su.x & 0xffff) + ax * inv + bb.x, 0.f);
        float ry = fmaxf(bfbits2f(su.x >> 16)    + ay * inv + bb.y, 0.f);
        float rz = fmaxf(bfbits2f(su.y & 0xffff) + az * inv + bb.z, 0.f);
        float rw = fmaxf(bfbits2f(su.y >> 16)    + aw * inv + bb.w, 0.f);
        uint2 pk;
        pk.x = pack2(rx, ry);
        pk.y = pack2(rz, rw);
        *(uint2*)(h1 + o) = pk;
    }
}

// ---------------- GEMM2: h1(bf16) [N,64] x [64,32] -> out(self) [N,16] f32, t2 [N,16] bf16 ----------------
// xs tile stays RAW bf16 (h1 already bf16 -> zero extra rounding). LDS 24.9KB -> 6 blk/CU.
__global__ __launch_bounds__(256) void gemm2_kernel(
    const bf16_t* __restrict__ h1, const float* __restrict__ Ws,
    const float* __restrict__ Wn, float* __restrict__ outp,
    bf16_t* __restrict__ t2, int N)
{
    __shared__ float Wc[64 * 32];              // 8 KB
    __shared__ unsigned short xsu[128 * XS_S]; // 17 KB raw bf16
    int t = threadIdx.x;
    int node0 = blockIdx.x * 128;

    for (int idx = t; idx < 64 * 32; idx += 256) {
        int k = idx >> 5, c = idx & 31;
        Wc[idx] = (c < 16) ? Ws[k * 16 + c] : Wn[k * 16 + (c - 16)];
    }
    for (int idx = t; idx < 128 * 8; idx += 256) {
        int row = idx >> 3, c8 = idx & 7;
        int node = node0 + row;
        uint2 lo = make_uint2(0u, 0u), hi = make_uint2(0u, 0u);
        if (node < N) {
            uint4 u = *(const uint4*)(h1 + (size_t)node * 64 + c8 * 8);
            lo.x = u.x; lo.y = u.y; hi.x = u.z; hi.y = u.w;
        }
        *(uint2*)(xsu + row * XS_S + c8 * 8)     = lo;   // byte row*136+c8*16: 8B-aligned
        *(uint2*)(xsu + row * XS_S + c8 * 8 + 4) = hi;
    }
    __syncthreads();

    int m = t & 31;
    int g = t >> 5;            // 8 col-groups of 4
    float acc[4][4];
#pragma unroll
    for (int j = 0; j < 4; ++j)
#pragma unroll
        for (int c = 0; c < 4; ++c) acc[j][c] = 0.f;

    for (int k = 0; k < 64; ++k) {
        float w[4];
        const float* wp = &Wc[k * 32 + g * 4];
#pragma unroll
        for (int c = 0; c < 4; ++c) w[c] = wp[c];
        float a0 = bfbits2f(xsu[m * XS_S + k]);
        float a1 = bfbits2f(xsu[(m + 32) * XS_S + k]);
        float a2 = bfbits2f(xsu[(m + 64) * XS_S + k]);
        float a3 = bfbits2f(xsu[(m + 96) * XS_S + k]);
#pragma unroll
        for (int c = 0; c < 4; ++c) {
            acc[0][c] += a0 * w[c];
            acc[1][c] += a1 * w[c];
            acc[2][c] += a2 * w[c];
            acc[3][c] += a3 * w[c];
        }
    }
#pragma unroll
    for (int j = 0; j < 4; ++j) {
        int node = node0 + m + 32 * j;
        if (node < N) {
            if (g < 4) {
                *(float4*)(outp + (size_t)node * 16 + g * 4) =
                    make_float4(acc[j][0], acc[j][1], acc[j][2], acc[j][3]);
            } else {
                uint2 pk;
                pk.x = pack2(acc[j][0], acc[j][1]);
                pk.y = pack2(acc[j][2], acc[j][3]);
                *(uint2*)(t2 + (size_t)node * 16 + (g - 4) * 4) = pk;
            }
        }
    }
}

// ---------------- gather16: out += (sum t2[src])/deg + b2 (R17-proven) ----------------
__global__ __launch_bounds__(256) void gather16_kernel(
    const int* __restrict__ csr, const int* __restrict__ cnt,
    const bf16_t* __restrict__ t2,
    float* __restrict__ outp, const float* __restrict__ b2, int N)
{
    int wid = (blockIdx.x * 256 + threadIdx.x) >> 6;
    int lane = threadIdx.x & 63;
    int eslot = lane >> 3;       // 0..7
    int c2 = lane & 7;           // cols [c2*2, c2*2+2)
    if (wid >= N) return;
    int eraw = csr[(size_t)wid * CAPN + lane];   // whole row, coalesced
    int d = cnt[wid];
    size_t o = (size_t)wid * 16 + c2 * 2;
    float2 oo = make_float2(0.f, 0.f), bbv = make_float2(0.f, 0.f);
    if (eslot == 0) {
        oo = *(const float2*)(outp + o);
        bbv = *(const float2*)(b2 + c2 * 2);
    }
    d = min(d, CAPN);
    float a0 = 0.f, a1 = 0.f;
    if (d > 0) {
        int dm1 = d - 1;
#define G16_BATCH(KN)                                                      \
        {                                                                  \
            int ss[KN]; float mk[KN]; unsigned uu[KN];                     \
            _Pragma("unroll")                                              \
            for (int k = 0; k < KN; ++k) {                                 \
                int i = eslot + 8 * k;                                     \
                int idx = i > dm1 ? dm1 : i;                               \
                mk[k] = (i <= dm1) ? 1.f : 0.f;                            \
                ss[k] = __shfl(eraw, idx);                                 \
            }                                                              \
            _Pragma("unroll")                                              \
            for (int k = 0; k < KN; ++k)                                   \
                uu[k] = *(const unsigned*)(t2 + (size_t)ss[k] * 16 + c2 * 2); \
            _Pragma("unroll")                                              \
            for (int k = 0; k < KN; ++k) {                                 \
                a0 += mk[k] * bfbits2f(uu[k] & 0xffff);                    \
                a1 += mk[k] * bfbits2f(uu[k] >> 16);                       \
            }                                                              \
        }
        if (d <= 16) {
            G16_BATCH(2)
        } else if (d <= 32) {
            G16_BATCH(4)
        } else {
            G16_BATCH(8)
        }
#undef G16_BATCH
        a0 += __shfl_xor(a0, 8);  a1 += __shfl_xor(a1, 8);
        a0 += __shfl_xor(a0, 16); a1 += __shfl_xor(a1, 16);
        a0 += __shfl_xor(a0, 32); a1 += __shfl_xor(a1, 32);
    }
    if (eslot == 0) {
        float inv = 1.f / fmaxf((float)d, 1.f);
        float2 r;
        r.x = oo.x + a0 * inv + bbv.x;
        r.y = oo.y + a1 * inv + bbv.y;
        *(float2*)(outp + o) = r;
    }
}

extern "C" void kernel_launch(void* const* d_in, const int* in_sizes, int n_in,
                              void* d_out, int out_size, void* d_ws, size_t ws_size,
                              hipStream_t stream) {
    const float* x   = (const float*)d_in[0];
    const int*   src = (const int*)d_in[1];
    const int*   dst = (const int*)d_in[2];
    const float* Ws1 = (const float*)d_in[3];
    const float* Wn1 = (const float*)d_in[4];
    const float* b1  = (const float*)d_in[5];
    const float* Ws2 = (const float*)d_in[6];
    const float* Wn2 = (const float*)d_in[7];
    const float* b2  = (const float*)d_in[8];
    float* outp = (float*)d_out;

    const int N = in_sizes[0] / FEATS;   // 50000
    const int E = in_sizes[1];           // 800000
    const int B = (N + 255) / 256;       // buckets (196) — must be <= 256
    const int NBP = (E + 256 * EPT - 1) / (256 * EPT);   // partition blocks (196)
    const int NBG = (N + 127) / 128;                     // gemm1 blocks (391)

    // workspace: bucket_cnt[256] | epart[B*CAP] | cnt[N] | csr[N*CAPN] |
    //            selfo bf16[N*64] | t1 fp8[N*64] | h1 bf16[N*64] | t2 bf16[N*16]
    char* p = (char*)d_ws;
    auto align16 = [](char* q) { return (char*)(((size_t)q + 15) & ~(size_t)15); };
    int* bucket_cnt    = (int*)p;                  p = (char*)(bucket_cnt + 256);
    int* epart         = (int*)p;                  p = (char*)(epart + (size_t)B * CAP);
    int* cnt           = (int*)align16(p);         p = (char*)(cnt + N);
    int* csr           = (int*)align16(p);         p = (char*)(csr + (size_t)N * CAPN);
    bf16_t* selfo      = (bf16_t*)align16(p);      p = (char*)(selfo + (size_t)N * 64);
    unsigned char* t1  = (unsigned char*)align16(p); p = (char*)(t1 + (size_t)N * 64);
    bf16_t* h1         = (bf16_t*)align16(p);      p = (char*)(h1 + (size_t)N * 64);
    bf16_t* t2         = (bf16_t*)align16(p);

    hipMemsetAsync(bucket_cnt, 0, 256 * sizeof(int), stream);

    fused_pg_kernel<<<NBP + NBG, 256, 0, stream>>>(
        src, dst, bucket_cnt, epart, E, x, Ws1, Wn1, selfo, t1, N, NBP);
    buildcsr_kernel<<<B, 256, 0, stream>>>(epart, bucket_cnt, cnt, csr, N);

    gather64_kernel<<<((size_t)N * 64 + 255) / 256, 256, 0, stream>>>(
        csr, cnt, t1, selfo, h1, b1, N);
    gemm2_kernel<<<(N + 127) / 128, 256, 0, stream>>>(h1, Ws2, Wn2, outp, t2, N);
    gather16_kernel<<<((size_t)N * 64 + 255) / 256, 256, 0, stream>>>(
        csr, cnt, t2, outp, b2, N);
}